// Round 6
// baseline (696.500 us; speedup 1.0000x reference)
//
#include <hip/hip_runtime.h>

// HistLoss: per-channel histogram matching + MSE loss.
// C=64, H=W=512, HW=262144, NBINS=256, STRENGTH=100.
//
// R15: fusion with R12's parallel shapes restored. R14 post-mortem:
// k_fused 201us, Occupancy 45.7% (1 blk/CU = 16 waves vs pipeline's 32),
// VALU 11%, HBM 7% -- parallelism loss, not a bandwidth/compute wall.
// Now: grid 1024 blk x 512 thr = 4 blk/CU (fully resident, required for
// spin-sync; __launch_bounds__(512,8) pins VGPR<=64, LDS ~37KB), NSL=16
// slices/channel = R12 pass1 geometry (47us measured).
//  P1: pass1 verbatim (bit-identical qacc grouping, 32px/thread):
//      buk LDS stats -> pc partials (32MB), qtot per 512-bucket group
//      (shfl half-wave reduce, no LDS), J minmax, popcount nI/nJ, Q_c.
//  sync1[c]: threadfence + atomicAdd; spin to 16 (resident => safe).
//  P2: channel minmax -> 256-bin hist of own J slice (L2/L3-hot),
//      LDS h (overlay on buk) -> ghist atomicAdd. sync2[c].
//  P3: closs, 1 bucket/thread (512x16=8192): hsum/serial f32 cumsum
//      (ref rounding), analytic remap, f64 loss atomic, donecnt -> out.
// Cross-block reads via device-scope atomic RMW (R14-proven protocol).
// absmax 0.0 expected (R12-identical math; R14 passed same protocol).

#define CN    64
#define HWN   262144
#define NB    256
#define NBUK  8192
#define NSL   16                  // slices (blocks) per channel
#define SPIX  (HWN/NSL)           // 16384 pixels per block
#define FT    512                 // fused threads
#define GBUK  (NBUK/NSL)          // 512 buckets per block in P3
#define FXS2  268435456.0f        // 2^28 fixed-point scale for sum(v-center)
#define FXSI2 (1.0/268435456.0)

// Pack int32 {0,1} masks to 1 bit/pixel; zero per-iteration state.
__global__ __launch_bounds__(256) void k_bits(
    const int* __restrict__ mI, const int* __restrict__ mJ,
    unsigned char* __restrict__ bI, unsigned char* __restrict__ bJ,
    unsigned* __restrict__ ghist, unsigned* __restrict__ syncbuf,
    double* __restrict__ lossacc, unsigned* __restrict__ donecnt)
{
  const int t = blockIdx.x*256 + threadIdx.x;
  if(blockIdx.x < 64){
    ghist[blockIdx.x*NB + threadIdx.x] = 0u;         // 64 ch x 256 bins
  } else if(blockIdx.x == 64){
    for(int i = threadIdx.x; i < 2048; i += 256) syncbuf[i] = 0u;
    if(threadIdx.x == 0){ *lossacc = 0.0; *donecnt = 0u; }
  }
  const int4* a = (const int4*)mI + 2*t;
  int4 x0 = a[0], x1 = a[1];
  unsigned b = (unsigned)((x0.x>0) | ((x0.y>0)<<1) | ((x0.z>0)<<2) | ((x0.w>0)<<3)
             | ((x1.x>0)<<4) | ((x1.y>0)<<5) | ((x1.z>0)<<6) | ((x1.w>0)<<7));
  const int4* c = (const int4*)mJ + 2*t;
  int4 y0 = c[0], y1 = c[1];
  unsigned d = (unsigned)((y0.x>0) | ((y0.y>0)<<1) | ((y0.z>0)<<2) | ((y0.w>0)<<3)
             | ((y1.x>0)<<4) | ((y1.y>0)<<5) | ((y1.z>0)<<6) | ((y1.w>0)<<7));
  bI[t] = (unsigned char)b;
  bJ[t] = (unsigned char)d;
}

__device__ __forceinline__ void px_i(float v, float& qacc, unsigned* buk){
  int k = (int)(v * (float)NBUK);                    // pow2 scale: exact, monotone
  if(k > NBUK-1) k = NBUK-1;
  float dv = v - ((float)k + 0.5f) * (1.0f/(float)NBUK);
  int fx = (int)rintf(dv * FXS2);                    // |fx| <= 16384
  atomicAdd(&buk[k], ((unsigned)fx << 12) + 1u);
  qacc += dv*dv;
}

__device__ __forceinline__ void grp_p1(float4 vi, float4 vj,
    unsigned bI4, unsigned bJ4, float& qacc, unsigned& mn, unsigned& mx,
    unsigned* buk){
  if(bI4 & 1u) px_i(vi.x, qacc, buk);
  if(bI4 & 2u) px_i(vi.y, qacc, buk);
  if(bI4 & 4u) px_i(vi.z, qacc, buk);
  if(bI4 & 8u) px_i(vi.w, qacc, buk);
  if(bJ4 & 1u){unsigned u=__float_as_uint(vj.x); mn=min(mn,u); mx=max(mx,u);}
  if(bJ4 & 2u){unsigned u=__float_as_uint(vj.y); mn=min(mn,u); mx=max(mx,u);}
  if(bJ4 & 4u){unsigned u=__float_as_uint(vj.z); mn=min(mn,u); mx=max(mx,u);}
  if(bJ4 & 8u){unsigned u=__float_as_uint(vj.w); mn=min(mn,u); mx=max(mx,u);}
}

__global__ __launch_bounds__(FT, 8) void k_fused(
    const float* __restrict__ I, const float* __restrict__ J,
    const unsigned* __restrict__ bI, const unsigned* __restrict__ bJ,
    unsigned* pc, unsigned* qtot, unsigned* mnp, unsigned* mxp,
    unsigned* cip, unsigned* cjp, double* qp, unsigned* ghist,
    unsigned* sync1, unsigned* sync2,
    double* lossacc, unsigned* donecnt, float* out)
{
  const int c = blockIdx.y, qt = blockIdx.x, tid = threadIdx.x;
  const int bid = c*NSL + qt;
  const int wid = tid >> 6, lane = tid & 63;
  __shared__ unsigned buk[NBUK];                    // 32KB; overlaid in P2/P3
  __shared__ unsigned smbI[SPIX/32], smbJ[SPIX/32]; // 512 words each
  __shared__ double dred[FT/64];
  __shared__ unsigned umn[FT/64], umx[FT/64], uci[FT/64], ucj[FT/64];
  __shared__ double red2[FT/64];
  __shared__ float sh_mn, sh_den, sh_st;
  __shared__ unsigned sh_base;
  // overlays into buk (free after P1's last read):
  unsigned* h    = buk;                              // [256] P2 hist
  float*    cs   = (float*)(buk + 256);              // [256] cumsum
  float*    hs   = (float*)(buk + 512);              // [256] scaled hist
  unsigned* hsum = buk + 768;                        // [256]
  unsigned* qsh  = buk + 1024;                       // [256] 16 sl x 16 grp
  unsigned* wsum = buk + 1280;                       // [8]

  // ---- stage bits (own slice), popcount for nI/nJ ----
  unsigned s0 = bI[qt*(SPIX/32) + tid];              // FT == SPIX/32 == 512
  unsigned t0 = bJ[qt*(SPIX/32) + tid];
  smbI[tid] = s0; smbJ[tid] = t0;
  unsigned ci = __popc(s0), cj = __popc(t0);
  #pragma unroll
  for(int i = 0; i < NBUK/FT; i++) buk[i*FT + tid] = 0u;
  __syncthreads();

  // ---- P1: I-buckets + J minmax (R12 pass1 geometry) ----
  const float4* Ic = (const float4*)(I + (size_t)c*HWN + (size_t)qt*SPIX);
  const float4* Jc = (const float4*)(J + (size_t)c*HWN + (size_t)qt*SPIX);
  float qacc = 0.0f;
  unsigned mn = 0x7F800000u, mx = 0u;
  const int nsh = (tid & 7) * 4;
  const int bw  = tid >> 3;
  #pragma unroll
  for(int g = 0; g < 8; g++){
    float4 vi = Ic[g*FT + tid];
    float4 vj = Jc[g*FT + tid];
    unsigned bI4 = (smbI[g*64 + bw] >> nsh) & 0xFu;
    unsigned bJ4 = (smbJ[g*64 + bw] >> nsh) & 0xFu;
    grp_p1(vi, vj, bI4, bJ4, qacc, mn, mx, buk);
  }
  __syncthreads();                                   // LDS atomics complete

  { unsigned* pcb = pc + (size_t)bid * NBUK;         // pc partial
    #pragma unroll
    for(int i = 0; i < NBUK/FT; i++) pcb[i*FT + tid] = buk[i*FT + tid]; }

  // qtot per 512-bucket group: thread sums buk[t*16..+15] (group = tid>>5,
  // 32 consecutive tids = half-wave), shfl tree reduce, lanes 0/32 write
  { unsigned csum = 0;
    #pragma unroll
    for(int j = 0; j < 16; j++) csum += buk[tid*16 + j] & 0xFFFu;
    csum += __shfl_down(csum, 16, 64);
    csum += __shfl_down(csum,  8, 64);
    csum += __shfl_down(csum,  4, 64);
    csum += __shfl_down(csum,  2, 64);
    csum += __shfl_down(csum,  1, 64);
    if((tid & 31) == 0) qtot[bid*16 + (tid >> 5)] = csum;
  }

  double qd = (double)qacc;
  for(int o = 32; o > 0; o >>= 1){
    qd += __shfl_down(qd, o, 64);
    mn  = min(mn, (unsigned)__shfl_down(mn, o, 64));
    mx  = max(mx, (unsigned)__shfl_down(mx, o, 64));
    ci += __shfl_down(ci, o, 64);
    cj += __shfl_down(cj, o, 64);
  }
  if(lane == 0){ dred[wid]=qd; umn[wid]=mn; umx[wid]=mx; uci[wid]=ci; ucj[wid]=cj; }
  __syncthreads();
  if(tid == 0){
    double t = 0.0; unsigned amn=0x7F800000u, amx=0u, aci=0, acj=0;
    for(int w = 0; w < FT/64; w++){
      t += dred[w];
      amn = min(amn, umn[w]); amx = max(amx, umx[w]);
      aci += uci[w]; acj += ucj[w];
    }
    qp[bid] = t; mnp[bid] = amn; mxp[bid] = amx;
    cip[bid] = aci; cjp[bid] = acj;
  }

  // ---- release + per-channel sync (16 blocks; grid fully resident) ----
  __syncthreads();
  __threadfence();
  if(tid == 0){
    atomicAdd(&sync1[c*16], 1u);
    while(__hip_atomic_load(&sync1[c*16], __ATOMIC_ACQUIRE,
                            __HIP_MEMORY_SCOPE_AGENT) < (unsigned)NSL)
      __builtin_amdgcn_s_sleep(2);
  }
  __syncthreads();

  // ---- P2: channel minmax -> 256-bin J hist of own slice (cache-hot) ----
  if(tid < NB) h[tid] = 0u;                          // overlay on buk
  if(tid == 0){
    unsigned amn = 0x7F800000u, amx = 0u;
    for(int i = 0; i < NSL; i++){
      amn = min(amn, atomicOr(&mnp[c*NSL + i], 0u)); // device-scope RMW read
      amx = max(amx, atomicOr(&mxp[c*NSL + i], 0u));
    }
    float mnv = __uint_as_float(amn);
    float rng = __uint_as_float(amx) - mnv;
    sh_mn = mnv;
    sh_den = fmaxf(rng / (float)NB, 1e-12f);         // binning denom
    sh_st  = rng / (float)NB;                        // remap step (unclamped)
  }
  __syncthreads();
  { const float mnv = sh_mn, den = sh_den;
    #pragma unroll
    for(int g = 0; g < 8; g++){
      float4 v = Jc[g*FT + tid];                     // L2/L3-hot re-read
      unsigned b4 = (smbJ[g*64 + bw] >> nsh) & 0xFu;
      if(b4 & 1u){ float bf = floorf((v.x - mnv)/den);
        bf = fminf(fmaxf(bf,0.0f),255.0f); atomicAdd(&h[(int)bf],1u); }
      if(b4 & 2u){ float bf = floorf((v.y - mnv)/den);
        bf = fminf(fmaxf(bf,0.0f),255.0f); atomicAdd(&h[(int)bf],1u); }
      if(b4 & 4u){ float bf = floorf((v.z - mnv)/den);
        bf = fminf(fmaxf(bf,0.0f),255.0f); atomicAdd(&h[(int)bf],1u); }
      if(b4 & 8u){ float bf = floorf((v.w - mnv)/den);
        bf = fminf(fmaxf(bf,0.0f),255.0f); atomicAdd(&h[(int)bf],1u); }
    }
  }
  __syncthreads();
  if(tid < NB) atomicAdd(&ghist[c*NB + tid], h[tid]);
  __threadfence();
  if(tid == 0){
    atomicAdd(&sync2[c*16], 1u);
    while(__hip_atomic_load(&sync2[c*16], __ATOMIC_ACQUIRE,
                            __HIP_MEMORY_SCOPE_AGENT) < (unsigned)NSL)
      __builtin_amdgcn_s_sleep(2);
  }
  __syncthreads();

  // ---- P3: closs, 1 bucket/thread (b0 = qt*GBUK + tid) ----
  if(tid < NB){
    qsh[tid]  = atomicOr(&qtot[c*256 + tid], 0u);    // [sl*16+grp]
    hsum[tid] = atomicAdd(&ghist[c*NB + tid], 0u);
  }
  __syncthreads();
  if(tid == 0){
    unsigned ciw = 0, cjw = 0;
    for(int i = 0; i < NSL; i++){
      ciw += atomicOr(&cip[c*NSL + i], 0u);
      cjw += atomicOr(&cjp[c*NSL + i], 0u);
    }
    float ratio = (float)ciw / (float)cjw;           // nI/nJ in f32, as in ref
    float cum = 0.0f;
    for(int b = 0; b < NB; b++){
      float hh = (float)hsum[b] * ratio;
      hs[b] = hh;
      cum += hh;                                     // sequential f32 == ref rounding
      cs[b] = cum;
    }
    unsigned base = 0;
    for(int sl = 0; sl < NSL; sl++)
      for(int g2 = 0; g2 < qt; g2++) base += qsh[sl*16 + g2];
    sh_base = base;
  }
  __syncthreads();

  unsigned  kk = 0;
  long long ss = 0;
  for(int sl = 0; sl < NSL; sl++){
    unsigned w = atomicOr(&pc[(size_t)(c*NSL + sl)*NBUK + qt*GBUK + tid], 0u);
    kk += w & 0xFFFu;  ss += (int)w >> 12;           // sign-extend fx sum
  }
  unsigned v = kk;                                   // wave inclusive scan
  for(int o = 1; o < 64; o <<= 1){
    unsigned t = __shfl_up(v, o, 64);
    if(lane >= o) v += t;
  }
  if(lane == 63) wsum[wid] = v;
  __syncthreads();
  unsigned wbase = 0;
  for(int w = 0; w < wid; w++) wbase += wsum[w];
  unsigned texcl = sh_base + wbase + (v - kk);

  float  mnvf = sh_mn, stepf = sh_st;
  double mnvd = (double)mnvf, stepd = (double)stepf;

  float rf0 = (float)(texcl + 1u);                   // left-search start bin
  int lo = 0, hi = NB;
  while(lo < hi){ int mid = (lo + hi) >> 1; if(cs[mid] < rf0) lo = mid + 1; else hi = mid; }
  int bin = (lo > NB-1) ? NB-1 : lo;

  double acc = 0.0;
  if(kk){
    unsigned ra = texcl + 1u, rb = texcl + kk;
    double sval = 0.0;
    while(ra <= rb){
      while(bin < NB-1 && cs[bin] < (float)ra) bin++;
      float csb = cs[bin], hsb = hs[bin];
      unsigned re = (bin == NB-1) ? rb : min(rb, (unsigned)floorf(csb));
      double lovd = (double)csb - (double)hsb;
      double den2 = fmax((double)hsb, 1e-12);
      double ra_d = (double)ra, re_d = (double)re, nn = (double)(re - ra + 1u);
      double rta = (ra_d - lovd)/den2, rtb = (re_d - lovd)/den2;
      if(hsb > 0.0f && rta >= 0.0 && rtb <= 1.0){
        double sumr = 0.5*(ra_d + re_d)*nn;          // arithmetic series of ranks
        sval += nn*(mnvd + (double)bin*stepd) + stepd*(sumr - nn*lovd)/den2;
      } else {                                       // exact per-rank f32 fallback
        for(unsigned rr = ra; rr <= re; rr++){
          float rf = (float)rr;
          float lov = csb - hsb;
          float rt = (rf - lov) / fmaxf(hsb, 1e-12f);
          rt = fminf(fmaxf(rt, 0.0f), 1.0f);
          sval += (double)(mnvf + ((float)bin + rt)*stepf);
        }
      }
      ra = re + 1u;
    }
    double kb   = (double)kk;
    double cb   = ((double)(qt*GBUK + tid) + 0.5) * (1.0/(double)NBUK);
    double vbar = sval/kb - cb;                      // mean(val) - bucket center
    double S    = (double)ss * FXSI2;                // sum(v - center)
    acc = kb*vbar*vbar - 2.0*vbar*S;
  }
  if(qt == 0 && tid == 0){                           // Q_c once per channel
    double qsum = 0.0;
    for(int qi = 0; qi < NSL; qi++)
      qsum += atomicAdd(&qp[c*NSL + qi], 0.0);
    acc += qsum;
  }
  for(int o = 32; o > 0; o >>= 1) acc += __shfl_down(acc, o, 64);
  if(lane == 0) red2[wid] = acc;
  __syncthreads();
  if(tid == 0){
    double t = 0.0;
    for(int w = 0; w < FT/64; w++) t += red2[w];
    atomicAdd(lossacc, t);
    __threadfence();
    unsigned old = atomicAdd(donecnt, 1u);
    if(old == (unsigned)(CN*NSL - 1)){               // last block finalizes
      double tot = atomicAdd(lossacc, 0.0);          // coherent read
      out[0] = (float)(tot * (100.0 / (double)((size_t)CN * HWN)));
    }
  }
}

extern "C" void kernel_launch(void* const* d_in, const int* in_sizes, int n_in,
                              void* d_out, int out_size, void* d_ws, size_t ws_size,
                              hipStream_t stream){
  const float* I  = (const float*)d_in[0];
  const float* J  = (const float*)d_in[1];
  const int*   mI = (const int*)d_in[2];
  const int*   mJ = (const int*)d_in[3];
  float* out = (float*)d_out;

  char* base = (char*)d_ws;
  size_t pcB = (size_t)CN * NSL * NBUK * sizeof(unsigned);       // 32 MB
  unsigned* pc      = (unsigned*)base;
  char* p = base + pcB;
  double*   qp      = (double*)p;   p += (size_t)CN*NSL*sizeof(double);
  double*   lossacc = (double*)p;   p += sizeof(double);
  unsigned* qtot    = (unsigned*)p; p += (size_t)CN*NSL*16*sizeof(unsigned);
  unsigned* mnp     = (unsigned*)p; p += (size_t)CN*NSL*sizeof(unsigned);
  unsigned* mxp     = (unsigned*)p; p += (size_t)CN*NSL*sizeof(unsigned);
  unsigned* cip     = (unsigned*)p; p += (size_t)CN*NSL*sizeof(unsigned);
  unsigned* cjp     = (unsigned*)p; p += (size_t)CN*NSL*sizeof(unsigned);
  unsigned* ghist   = (unsigned*)p; p += (size_t)CN*NB*sizeof(unsigned);
  unsigned* syncbuf = (unsigned*)p; p += 2048*sizeof(unsigned);  // sync1|sync2
  unsigned* donecnt = (unsigned*)p; p += sizeof(unsigned);
  size_t off = (size_t)(p - base); off = (off + 15) & ~(size_t)15;
  unsigned char* bIb = (unsigned char*)(base + off);             // 32 KB bitmask
  unsigned char* bJb = bIb + HWN/8;                              // 32 KB bitmask
  unsigned* sync1 = syncbuf;
  unsigned* sync2 = syncbuf + 1024;

  k_bits<<<HWN/(8*256), 256, 0, stream>>>(mI, mJ, bIb, bJb, ghist, syncbuf,
                                          lossacc, donecnt);
  k_fused<<<dim3(NSL, CN), FT, 0, stream>>>(I, J, (const unsigned*)bIb,
                                            (const unsigned*)bJb, pc, qtot,
                                            mnp, mxp, cip, cjp, qp, ghist,
                                            sync1, sync2, lossacc, donecnt, out);
}

// Round 7
// 361.442 us; speedup vs baseline: 1.9270x; 1.9270x over previous
//
#include <hip/hip_runtime.h>

// HistLoss: per-channel histogram matching + MSE loss.
// C=64, H=W=512, HW=262144, NBINS=256, STRENGTH=100.
//
// R16: partial fusion, evidence-driven. R15 post-mortem: full fusion
// stalled at 500us with ALL pipes <6% -- the 8.4M device-scope
// atomic-RMW reads of pc (32MB) serialized at the coherence point
// (WRITE_SIZE 10.6->86MB is the RMW write-half). Lesson: cross-block
// bulk data must cross a KERNEL BOUNDARY (free coherence); in-kernel
// sync is only viable for tiny state (R14: 256-word hist, worked).
// Structure: k_bits + k_pass1 (R12-exact, 47-50us measured; only qtot
// 4->16 groups via half-wave shfl, integer-exact) + k_hc:
//   phase A (histJ): 16 blk/ch x 512 thr, own 16K-px slice of J
//     (bit-mask LDS), 2 sub-hists -> ghist atomicAdd (256/block);
//     threadfence + sync1[c] spin to 16 (grid fully resident).
//   phase B (closs): 1 bucket/thread (16x512=8192), pc via PLAIN
//     coalesced loads (kernel boundary after pass1 => coherent),
//     qtot/mnp/mxp/cp/qp plain; ghist via atomic reads (tiny).
//     Math verbatim from R15 P3 (refchecked absmax 0.0).
// Removes: one launch gap, hisPart roundtrip, closs hsum re-reduce.

#define CN    64
#define HWN   262144
#define NB    256
#define NBUK  8192
#define NBLK  16                  // pass1 slices per channel
#define BPIX  (HWN/NBLK)          // 16384 pixels per pass1 block
#define PT    512                 // pass1 threads
#define NXB   16                  // k_hc blocks per channel
#define SPIX  (HWN/NXB)           // 16384 pixels per k_hc block
#define GBUK  (NBUK/NXB)          // 512 buckets per k_hc block (phase B)
#define FXS2  268435456.0f        // 2^28 fixed-point scale for sum(v-center)
#define FXSI2 (1.0/268435456.0)

// Pack int32 {0,1} masks to 1 bit/pixel; zero per-iteration state.
__global__ __launch_bounds__(256) void k_bits(
    const int* __restrict__ mI, const int* __restrict__ mJ,
    unsigned char* __restrict__ bI, unsigned char* __restrict__ bJ,
    unsigned* __restrict__ ghist, unsigned* __restrict__ syncbuf,
    double* __restrict__ lossacc, unsigned* __restrict__ donecnt)
{
  const int t = blockIdx.x*256 + threadIdx.x;
  if(blockIdx.x < 64){
    ghist[blockIdx.x*NB + threadIdx.x] = 0u;         // 64 ch x 256 bins
  } else if(blockIdx.x == 64){
    for(int i = threadIdx.x; i < 2048; i += 256) syncbuf[i] = 0u;
    if(threadIdx.x == 0){ *lossacc = 0.0; *donecnt = 0u; }
  }
  const int4* a = (const int4*)mI + 2*t;
  int4 x0 = a[0], x1 = a[1];
  unsigned b = (unsigned)((x0.x>0) | ((x0.y>0)<<1) | ((x0.z>0)<<2) | ((x0.w>0)<<3)
             | ((x1.x>0)<<4) | ((x1.y>0)<<5) | ((x1.z>0)<<6) | ((x1.w>0)<<7));
  const int4* c = (const int4*)mJ + 2*t;
  int4 y0 = c[0], y1 = c[1];
  unsigned d = (unsigned)((y0.x>0) | ((y0.y>0)<<1) | ((y0.z>0)<<2) | ((y0.w>0)<<3)
             | ((y1.x>0)<<4) | ((y1.y>0)<<5) | ((y1.z>0)<<6) | ((y1.w>0)<<7));
  bI[t] = (unsigned char)b;
  bJ[t] = (unsigned char)d;
}

__device__ __forceinline__ void px_i(float v, float& qacc, unsigned& ci,
                                     unsigned* buk){
  int k = (int)(v * (float)NBUK);                    // pow2 scale: exact, monotone
  if(k > NBUK-1) k = NBUK-1;
  float dv = v - ((float)k + 0.5f) * (1.0f/(float)NBUK);
  int fx = (int)rintf(dv * FXS2);                    // |fx| <= 16384
  atomicAdd(&buk[k], ((unsigned)fx << 12) + 1u);
  qacc += dv*dv;
  ci++;
}

__device__ __forceinline__ void grp_p1(float4 vi4, float4 vj4,
    unsigned bitsI, unsigned bitsJ, float& qacc, unsigned& ci, unsigned& cj,
    unsigned& mn, unsigned& mx, unsigned* buk){
  if(bitsI & 1u) px_i(vi4.x, qacc, ci, buk);
  if(bitsI & 2u) px_i(vi4.y, qacc, ci, buk);
  if(bitsI & 4u) px_i(vi4.z, qacc, ci, buk);
  if(bitsI & 8u) px_i(vi4.w, qacc, ci, buk);
  if(bitsJ & 1u){unsigned u=__float_as_uint(vj4.x); mn=min(mn,u); mx=max(mx,u); cj++;}
  if(bitsJ & 2u){unsigned u=__float_as_uint(vj4.y); mn=min(mn,u); mx=max(mx,u); cj++;}
  if(bitsJ & 4u){unsigned u=__float_as_uint(vj4.z); mn=min(mn,u); mx=max(mx,u); cj++;}
  if(bitsJ & 8u){unsigned u=__float_as_uint(vj4.w); mn=min(mn,u); mx=max(mx,u); cj++;}
}

__global__ __launch_bounds__(PT, 2) void k_pass1(
    const float* __restrict__ I, const float* __restrict__ J,
    const unsigned* __restrict__ bI, const unsigned* __restrict__ bJ,
    unsigned* __restrict__ pc, unsigned* __restrict__ qtot,
    unsigned* __restrict__ mnp, unsigned* __restrict__ mxp,
    unsigned* __restrict__ cp, double* __restrict__ qp)
{
  const int c = blockIdx.y, q = blockIdx.x, tid = threadIdx.x;
  const int bid = c*NBLK + q;
  const int wid = tid >> 6, lane = tid & 63;
  __shared__ unsigned buk[NBUK];                    // packed (fx<<12)+count
  __shared__ unsigned smbI[BPIX/32], smbJ[BPIX/32]; // 512 words each: slice bits
  __shared__ double   dred[PT/64];
  __shared__ unsigned umn[PT/64], umx[PT/64], uci[PT/64], ucj[PT/64];
  for(int i = tid; i < NBUK; i += PT) buk[i] = 0u;
  smbI[tid] = bI[q*(BPIX/32) + tid];                // PT == BPIX/32 == 512
  smbJ[tid] = bJ[q*(BPIX/32) + tid];
  __syncthreads();

  const float4* Ic = (const float4*)(I + (size_t)c*HWN + (size_t)q*BPIX);
  const float4* Jc = (const float4*)(J + (size_t)c*HWN + (size_t)q*BPIX);

  float qacc = 0.0f;
  unsigned ci = 0, cj = 0;
  unsigned mn = 0x7F800000u, mx = 0u;
  const int nsh = (tid & 7) * 4;                    // nibble shift, const/thread
  const int bw  = tid >> 3;

  float4 pi[2], pj[2];                              // 2-deep reg pipeline (R12)
  pi[0] = Ic[tid]; pj[0] = Jc[tid];
  #pragma unroll
  for(int g = 0; g < 8; g++){
    const int cur = g & 1, nxt = cur ^ 1;
    if(g < 7){ pi[nxt] = Ic[(g+1)*PT + tid]; pj[nxt] = Jc[(g+1)*PT + tid]; }
    const unsigned bitsI = (smbI[g*64 + bw] >> nsh) & 0xFu;
    const unsigned bitsJ = (smbJ[g*64 + bw] >> nsh) & 0xFu;
    grp_p1(pi[cur], pj[cur], bitsI, bitsJ, qacc, ci, cj, mn, mx, buk);
  }
  __syncthreads();                                   // LDS atomics complete
  { unsigned* pcb = pc + (size_t)bid * NBUK;
    for(int i = tid; i < NBUK; i += PT) pcb[i] = buk[i]; }

  // qtot: 16 groups of 512 buckets; 32 consecutive threads (16 buckets
  // each) = half-wave, shfl tree reduce (integer-exact)
  { unsigned csum = 0;
    #pragma unroll
    for(int j = 0; j < 16; j++) csum += buk[tid*16 + j] & 0xFFFu;
    csum += __shfl_down(csum, 16, 64);
    csum += __shfl_down(csum,  8, 64);
    csum += __shfl_down(csum,  4, 64);
    csum += __shfl_down(csum,  2, 64);
    csum += __shfl_down(csum,  1, 64);
    if((tid & 31) == 0) qtot[bid*16 + (tid >> 5)] = csum;
  }

  double qd = (double)qacc;
  for(int o = 32; o > 0; o >>= 1){
    qd += __shfl_down(qd, o, 64);
    mn  = min(mn, (unsigned)__shfl_down(mn, o, 64));
    mx  = max(mx, (unsigned)__shfl_down(mx, o, 64));
    ci += __shfl_down(ci, o, 64);
    cj += __shfl_down(cj, o, 64);
  }
  if(lane == 0){ dred[wid]=qd; umn[wid]=mn; umx[wid]=mx; uci[wid]=ci; ucj[wid]=cj; }
  __syncthreads();
  if(tid == 0){
    double t = 0.0; unsigned amn=0x7F800000u, amx=0u, aci=0, acj=0;
    for(int w = 0; w < PT/64; w++){
      t += dred[w];
      amn = min(amn, umn[w]); amx = max(amx, umx[w]);
      aci += uci[w]; acj += ucj[w];
    }
    qp[bid] = t;
    mnp[bid] = amn; mxp[bid] = amx;
    if(c == 0){ cp[2*q] = aci; cp[2*q+1] = acj; }
  }
}

// histJ + closs fused; only cross-block state is the 256-bin hist.
__global__ __launch_bounds__(512, 8) void k_hc(
    const float* __restrict__ J, const unsigned* __restrict__ bJ,
    const unsigned* __restrict__ pc, const unsigned* __restrict__ qtot,
    const unsigned* __restrict__ mnp, const unsigned* __restrict__ mxp,
    const unsigned* __restrict__ cp, const double* __restrict__ qp,
    unsigned* ghist, unsigned* sync1,
    double* lossacc, unsigned* donecnt, float* out)
{
  const int c = blockIdx.y, qt = blockIdx.x, tid = threadIdx.x;
  const int wid = tid >> 6, lane = tid & 63;
  __shared__ unsigned smb[SPIX/32];                  // 512 words: slice bits
  __shared__ unsigned h2[2][NB];                     // sub-hists
  __shared__ unsigned hsum[NB], qsh[NB];
  __shared__ float cs[NB], hs[NB];
  __shared__ unsigned wsum[8];
  __shared__ double red2[8];
  __shared__ float sh_mn, sh_den, sh_st;
  __shared__ unsigned sh_base;

  // ---- phase A: channel minmax -> own-slice 256-bin J histogram ----
  if(tid == 0){
    unsigned amn = 0x7F800000u, amx = 0u;
    for(int i = 0; i < NBLK; i++){                   // pass1 outputs: plain loads
      amn = min(amn, mnp[c*NBLK + i]);
      amx = max(amx, mxp[c*NBLK + i]);
    }
    float mnv = __uint_as_float(amn);
    float rng = __uint_as_float(amx) - mnv;
    sh_mn  = mnv;
    sh_den = fmaxf(rng / (float)NB, 1e-12f);         // binning denom (clamped)
    sh_st  = rng / (float)NB;                        // remap step (unclamped)
  }
  smb[tid] = bJ[qt*(SPIX/32) + tid];                 // 512 threads == 512 words
  h2[0][tid & 255] = 0u;                             // zero both sub-hists
  if(tid < NB*2 - 512) {}                            // (512 threads cover 512 slots)
  h2[1][tid & 255] = 0u;
  __syncthreads();
  { const float mnv = sh_mn, den = sh_den;
    const int nsh = (tid & 7) * 4;
    const int bw  = tid >> 3;
    unsigned* hh = h2[wid & 1];
    const float4* Jc = (const float4*)(J + (size_t)c*HWN + (size_t)qt*SPIX);
    #pragma unroll
    for(int g = 0; g < 8; g++){
      float4 v = Jc[g*512 + tid];
      unsigned b4 = (smb[g*64 + bw] >> nsh) & 0xFu;
      if(b4 & 1u){ float bf = floorf((v.x - mnv)/den);
        bf = fminf(fmaxf(bf,0.0f),255.0f); atomicAdd(&hh[(int)bf],1u); }
      if(b4 & 2u){ float bf = floorf((v.y - mnv)/den);
        bf = fminf(fmaxf(bf,0.0f),255.0f); atomicAdd(&hh[(int)bf],1u); }
      if(b4 & 4u){ float bf = floorf((v.z - mnv)/den);
        bf = fminf(fmaxf(bf,0.0f),255.0f); atomicAdd(&hh[(int)bf],1u); }
      if(b4 & 8u){ float bf = floorf((v.w - mnv)/den);
        bf = fminf(fmaxf(bf,0.0f),255.0f); atomicAdd(&hh[(int)bf],1u); }
    }
  }
  __syncthreads();
  if(tid < NB) atomicAdd(&ghist[c*NB + tid], h2[0][tid] + h2[1][tid]);
  __threadfence();
  if(tid == 0){
    atomicAdd(&sync1[c*16], 1u);
    while(__hip_atomic_load(&sync1[c*16], __ATOMIC_ACQUIRE,
                            __HIP_MEMORY_SCOPE_AGENT) < (unsigned)NXB)
      __builtin_amdgcn_s_sleep(2);
  }
  __syncthreads();

  // ---- phase B: closs, 1 bucket/thread (b = qt*GBUK + tid) ----
  if(tid < NB){
    qsh[tid]  = qtot[c*256 + tid];                   // plain (pass1 output)
    hsum[tid] = atomicOr(&ghist[c*NB + tid], 0u);    // coherent (tiny)
  }
  __syncthreads();
  if(tid == 0){
    unsigned ciw = 0, cjw = 0;
    for(int qi = 0; qi < NBLK; qi++){ ciw += cp[2*qi]; cjw += cp[2*qi+1]; }
    float ratio = (float)ciw / (float)cjw;           // nI/nJ in f32, as in ref
    float cum = 0.0f;
    for(int b = 0; b < NB; b++){
      float hh = (float)hsum[b] * ratio;
      hs[b] = hh;
      cum += hh;                                     // sequential f32 == ref rounding
      cs[b] = cum;
    }
    unsigned base = 0;
    for(int sl = 0; sl < NBLK; sl++)
      for(int g2 = 0; g2 < qt; g2++) base += qsh[sl*16 + g2];
    sh_base = base;
  }
  __syncthreads();

  unsigned  kk = 0;
  long long ss = 0;
  for(int sl = 0; sl < NBLK; sl++){
    unsigned w = pc[(size_t)(c*NBLK + sl)*NBUK + qt*GBUK + tid];  // plain, coalesced
    kk += w & 0xFFFu;  ss += (int)w >> 12;           // sign-extend fx sum
  }
  unsigned v = kk;                                   // wave inclusive scan
  for(int o = 1; o < 64; o <<= 1){
    unsigned t = __shfl_up(v, o, 64);
    if(lane >= o) v += t;
  }
  if(lane == 63) wsum[wid] = v;
  __syncthreads();
  unsigned wbase = 0;
  for(int w = 0; w < wid; w++) wbase += wsum[w];
  unsigned texcl = sh_base + wbase + (v - kk);

  float  mnvf = sh_mn, stepf = sh_st;
  double mnvd = (double)mnvf, stepd = (double)stepf;

  float rf0 = (float)(texcl + 1u);                   // left-search start bin
  int lo = 0, hi = NB;
  while(lo < hi){ int mid = (lo + hi) >> 1; if(cs[mid] < rf0) lo = mid + 1; else hi = mid; }
  int bin = (lo > NB-1) ? NB-1 : lo;

  double acc = 0.0;
  if(kk){
    unsigned ra = texcl + 1u, rb = texcl + kk;
    double sval = 0.0;
    while(ra <= rb){
      while(bin < NB-1 && cs[bin] < (float)ra) bin++;
      float csb = cs[bin], hsb = hs[bin];
      unsigned re = (bin == NB-1) ? rb : min(rb, (unsigned)floorf(csb));
      double lovd = (double)csb - (double)hsb;
      double den2 = fmax((double)hsb, 1e-12);
      double ra_d = (double)ra, re_d = (double)re, nn = (double)(re - ra + 1u);
      double rta = (ra_d - lovd)/den2, rtb = (re_d - lovd)/den2;
      if(hsb > 0.0f && rta >= 0.0 && rtb <= 1.0){
        double sumr = 0.5*(ra_d + re_d)*nn;          // arithmetic series of ranks
        sval += nn*(mnvd + (double)bin*stepd) + stepd*(sumr - nn*lovd)/den2;
      } else {                                       // exact per-rank f32 fallback
        for(unsigned rr = ra; rr <= re; rr++){
          float rf = (float)rr;
          float lov = csb - hsb;
          float rt = (rf - lov) / fmaxf(hsb, 1e-12f);
          rt = fminf(fmaxf(rt, 0.0f), 1.0f);
          sval += (double)(mnvf + ((float)bin + rt)*stepf);
        }
      }
      ra = re + 1u;
    }
    double kb   = (double)kk;
    double cb   = ((double)(qt*GBUK + tid) + 0.5) * (1.0/(double)NBUK);
    double vbar = sval/kb - cb;                      // mean(val) - bucket center
    double S    = (double)ss * FXSI2;                // sum(v - center)
    acc = kb*vbar*vbar - 2.0*vbar*S;
  }
  if(qt == 0 && tid == 0){                           // Q_c once per channel
    double qsum = 0.0;
    for(int qi = 0; qi < NBLK; qi++) qsum += qp[c*NBLK + qi];  // plain
    acc += qsum;
  }
  for(int o = 32; o > 0; o >>= 1) acc += __shfl_down(acc, o, 64);
  if(lane == 0) red2[wid] = acc;
  __syncthreads();
  if(tid == 0){
    double t = 0.0;
    for(int w = 0; w < 8; w++) t += red2[w];
    atomicAdd(lossacc, t);
    __threadfence();
    unsigned old = atomicAdd(donecnt, 1u);
    if(old == (unsigned)(CN*NXB - 1)){               // last block finalizes
      double tot = atomicAdd(lossacc, 0.0);          // coherent read
      out[0] = (float)(tot * (100.0 / (double)((size_t)CN * HWN)));
    }
  }
}

extern "C" void kernel_launch(void* const* d_in, const int* in_sizes, int n_in,
                              void* d_out, int out_size, void* d_ws, size_t ws_size,
                              hipStream_t stream){
  const float* I  = (const float*)d_in[0];
  const float* J  = (const float*)d_in[1];
  const int*   mI = (const int*)d_in[2];
  const int*   mJ = (const int*)d_in[3];
  float* out = (float*)d_out;

  char* base = (char*)d_ws;
  size_t pcB = (size_t)CN * NBLK * NBUK * sizeof(unsigned);      // 32 MB
  unsigned* pc      = (unsigned*)base;
  char* p = base + pcB;
  double*   qp      = (double*)p;   p += (size_t)CN*NBLK*sizeof(double);
  double*   lossacc = (double*)p;   p += sizeof(double);
  unsigned* qtot    = (unsigned*)p; p += (size_t)CN*NBLK*16*sizeof(unsigned);
  unsigned* mnp     = (unsigned*)p; p += (size_t)CN*NBLK*sizeof(unsigned);
  unsigned* mxp     = (unsigned*)p; p += (size_t)CN*NBLK*sizeof(unsigned);
  unsigned* cp      = (unsigned*)p; p += 2*NBLK*sizeof(unsigned);
  unsigned* ghist   = (unsigned*)p; p += (size_t)CN*NB*sizeof(unsigned);
  unsigned* syncbuf = (unsigned*)p; p += 2048*sizeof(unsigned);
  unsigned* donecnt = (unsigned*)p; p += sizeof(unsigned);
  size_t off = (size_t)(p - base); off = (off + 15) & ~(size_t)15;
  unsigned char* bIb = (unsigned char*)(base + off);             // 32 KB bitmask
  unsigned char* bJb = bIb + HWN/8;                              // 32 KB bitmask

  k_bits<<<HWN/(8*256), 256, 0, stream>>>(mI, mJ, bIb, bJb, ghist, syncbuf,
                                          lossacc, donecnt);
  k_pass1<<<dim3(NBLK, CN), PT, 0, stream>>>(I, J, (const unsigned*)bIb,
                                             (const unsigned*)bJb, pc, qtot,
                                             mnp, mxp, cp, qp);
  k_hc<<<dim3(NXB, CN), 512, 0, stream>>>(J, (const unsigned*)bJb, pc, qtot,
                                          mnp, mxp, cp, qp, ghist, syncbuf,
                                          lossacc, donecnt, out);
}

// Round 8
// 206.727 us; speedup vs baseline: 3.3692x; 1.7484x over previous
//
#include <hip/hip_runtime.h>

// HistLoss: per-channel histogram matching + MSE loss.
// C=64, H=W=512, HW=262144, NBINS=256, STRENGTH=100.
//
// R17: eliminate histJ WITHOUT in-kernel sync. Evidence: R14/R15/R16
// all show any cross-block spin barrier costs ~100+us of stall
// (R16: phaseA+phaseB = two <46us bodies glued by one spin = 220us,
// VALU 7.8%, HBM 3%). Only KERNEL BOUNDARIES may carry cross-block
// deps. histJ existed only because channel minmax came from pass1;
// moving minmax to a cheap J-only pre-kernel lets pass1 bin J into
// the 256-bin histogram in its existing loop (J already in regs) --
// the 64MB histJ re-read and one launch disappear, zero syncs.
//  k_prep (256blk x 512): pack mask bits (k_bits) + per-channel masked
//    J minmax partials[c][256] (wave-aligned channel groups, shfl
//    reduce, plain stores, no atomics/init). Zeroes lossacc/donecnt.
//  k_p1h = R12 pass1 (47-50us measured) + minmax partial reduce at
//    start + J 256-binning into 2 sub-hists (R16 phaseA rounding,
//    verified) -> hisPart[c][16][256]; per-slice minmax DROPPED.
//  k_closs = R16 phaseB verbatim (absmax 0.0) + hisPart reduce +
//    minmax partial reduce; all plain loads across boundaries.
// Bucket-mean pairing stands in for exact within-bucket ranks (absmax
// 0.0 R3-R16; threshold 2.9e-6).

#define CN    64
#define HWN   262144
#define NB    256
#define NBUK  8192
#define NBLK  16                  // slices per channel (k_p1h / k_closs)
#define BPIX  (HWN/NBLK)          // 16384 px per k_p1h block
#define PT    512
#define K1B   256                 // k_prep blocks
#define K1PIX (HWN/K1B)           // 1024 px per k_prep block
#define GBUK  (NBUK/NBLK)         // 512 buckets per k_closs block
#define FXS2  268435456.0f        // 2^28 fixed-point scale for sum(v-center)
#define FXSI2 (1.0/268435456.0)

// Pack masks to bits + per-channel masked J minmax partials.
__global__ __launch_bounds__(512) void k_prep(
    const float* __restrict__ J, const int* __restrict__ mI,
    const int* __restrict__ mJ, unsigned* __restrict__ bIw,
    unsigned* __restrict__ bJw, unsigned* __restrict__ mnp2,
    unsigned* __restrict__ mxp2, double* __restrict__ lossacc,
    unsigned* __restrict__ donecnt)
{
  const int b = blockIdx.x, tid = threadIdx.x;
  __shared__ unsigned sbJ[K1PIX/32];                 // 32 words
  if(tid < 32){                                      // word tid: px b*1024+tid*32
    const int4* mi4 = (const int4*)mI + (size_t)b*(K1PIX/4) + tid*8;
    const int4* mj4 = (const int4*)mJ + (size_t)b*(K1PIX/4) + tid*8;
    unsigned wi = 0u, wj = 0u;
    #pragma unroll
    for(int k = 0; k < 8; k++){
      int4 x = mi4[k];
      wi |= (unsigned)((x.x>0)|((x.y>0)<<1)|((x.z>0)<<2)|((x.w>0)<<3)) << (k*4);
      int4 y = mj4[k];
      wj |= (unsigned)((y.x>0)|((y.y>0)<<1)|((y.z>0)<<2)|((y.w>0)<<3)) << (k*4);
    }
    bIw[b*32 + tid] = wi;
    bJw[b*32 + tid] = wj;
    sbJ[tid] = wj;
  }
  if(b == 0 && tid == 0){ *lossacc = 0.0; *donecnt = 0u; }
  __syncthreads();
  // 8 passes x 8 wave-aligned channel groups; lanes cover the 1024-px slice
  const int grp = tid >> 6, lane = tid & 63;
  #pragma unroll
  for(int pass = 0; pass < 8; pass++){
    const int c = pass*8 + grp;
    const float4* Jc = (const float4*)(J + (size_t)c*HWN + (size_t)b*K1PIX);
    unsigned mn = 0x7F800000u, mx = 0u;
    #pragma unroll
    for(int k = 0; k < 4; k++){
      float4 v = Jc[k*64 + lane];                    // px (k*64+lane)*4, coalesced
      unsigned b4 = (sbJ[k*8 + (lane>>3)] >> ((lane&7)*4)) & 0xFu;
      if(b4 & 1u){unsigned u=__float_as_uint(v.x); mn=min(mn,u); mx=max(mx,u);}
      if(b4 & 2u){unsigned u=__float_as_uint(v.y); mn=min(mn,u); mx=max(mx,u);}
      if(b4 & 4u){unsigned u=__float_as_uint(v.z); mn=min(mn,u); mx=max(mx,u);}
      if(b4 & 8u){unsigned u=__float_as_uint(v.w); mn=min(mn,u); mx=max(mx,u);}
    }
    for(int o = 32; o > 0; o >>= 1){
      mn = min(mn, (unsigned)__shfl_down(mn, o, 64));
      mx = max(mx, (unsigned)__shfl_down(mx, o, 64));
    }
    if(lane == 0){ mnp2[c*K1B + b] = mn; mxp2[c*K1B + b] = mx; }
  }
}

__device__ __forceinline__ void px_i(float v, float& qacc, unsigned& ci,
                                     unsigned* buk){
  int k = (int)(v * (float)NBUK);                    // pow2 scale: exact, monotone
  if(k > NBUK-1) k = NBUK-1;
  float dv = v - ((float)k + 0.5f) * (1.0f/(float)NBUK);
  int fx = (int)rintf(dv * FXS2);                    // |fx| <= 16384
  atomicAdd(&buk[k], ((unsigned)fx << 12) + 1u);
  qacc += dv*dv;
  ci++;
}

// pass1 + J-histogram fused (minmax known from k_prep via boundary).
__global__ __launch_bounds__(PT, 2) void k_p1h(
    const float* __restrict__ I, const float* __restrict__ J,
    const unsigned* __restrict__ bIw, const unsigned* __restrict__ bJw,
    const unsigned* __restrict__ mnp2, const unsigned* __restrict__ mxp2,
    unsigned* __restrict__ pc, unsigned* __restrict__ qtot,
    unsigned* __restrict__ hisPart, unsigned* __restrict__ cp,
    double* __restrict__ qp)
{
  const int c = blockIdx.y, q = blockIdx.x, tid = threadIdx.x;
  const int bid = c*NBLK + q;
  const int wid = tid >> 6, lane = tid & 63;
  __shared__ unsigned buk[NBUK];                    // packed (fx<<12)+count
  __shared__ unsigned smbI[BPIX/32], smbJ[BPIX/32]; // 512 words each
  __shared__ unsigned h2[2][NB];                    // J-hist sub-hists
  __shared__ double   dred[PT/64];
  __shared__ unsigned uci[PT/64], ucj[PT/64];
  __shared__ unsigned rmn[4], rmx[4];
  __shared__ float sh_mn, sh_den;
  for(int i = tid; i < NBUK; i += PT) buk[i] = 0u;
  smbI[tid] = bIw[q*512 + tid];                     // PT == 512 words
  smbJ[tid] = bJw[q*512 + tid];
  if(tid < NB){ h2[0][tid] = 0u; h2[1][tid] = 0u; }
  if(tid < K1B){                                    // channel minmax reduce
    unsigned mn = mnp2[c*K1B + tid];
    unsigned mx = mxp2[c*K1B + tid];
    for(int o = 32; o > 0; o >>= 1){
      mn = min(mn, (unsigned)__shfl_down(mn, o, 64));
      mx = max(mx, (unsigned)__shfl_down(mx, o, 64));
    }
    if(lane == 0){ rmn[wid] = mn; rmx[wid] = mx; }
  }
  __syncthreads();
  if(tid == 0){
    unsigned mn = min(min(rmn[0],rmn[1]), min(rmn[2],rmn[3]));
    unsigned mx = max(max(rmx[0],rmx[1]), max(rmx[2],rmx[3]));
    float mnv = __uint_as_float(mn);
    sh_mn  = mnv;
    sh_den = fmaxf((__uint_as_float(mx) - mnv) / (float)NB, 1e-12f);
  }
  __syncthreads();

  const float4* Ic = (const float4*)(I + (size_t)c*HWN + (size_t)q*BPIX);
  const float4* Jc = (const float4*)(J + (size_t)c*HWN + (size_t)q*BPIX);
  const float mnv = sh_mn, den = sh_den;
  float qacc = 0.0f;
  unsigned ci = 0, cj = 0;
  const int nsh = (tid & 7) * 4;
  const int bw  = tid >> 3;
  unsigned* hh = h2[wid & 1];

  float4 pi[2], pj[2];                              // 2-deep reg pipeline (R12)
  pi[0] = Ic[tid]; pj[0] = Jc[tid];
  #pragma unroll
  for(int g = 0; g < 8; g++){
    const int cur = g & 1, nxt = cur ^ 1;
    if(g < 7){ pi[nxt] = Ic[(g+1)*PT + tid]; pj[nxt] = Jc[(g+1)*PT + tid]; }
    const unsigned bitsI = (smbI[g*64 + bw] >> nsh) & 0xFu;
    const unsigned bitsJ = (smbJ[g*64 + bw] >> nsh) & 0xFu;
    float4 vi = pi[cur], vj = pj[cur];
    if(bitsI & 1u) px_i(vi.x, qacc, ci, buk);
    if(bitsI & 2u) px_i(vi.y, qacc, ci, buk);
    if(bitsI & 4u) px_i(vi.z, qacc, ci, buk);
    if(bitsI & 8u) px_i(vi.w, qacc, ci, buk);
    if(bitsJ & 1u){ float bf = floorf((vj.x - mnv)/den);  // ref rounding
      bf = fminf(fmaxf(bf,0.0f),255.0f); atomicAdd(&hh[(int)bf],1u); cj++; }
    if(bitsJ & 2u){ float bf = floorf((vj.y - mnv)/den);
      bf = fminf(fmaxf(bf,0.0f),255.0f); atomicAdd(&hh[(int)bf],1u); cj++; }
    if(bitsJ & 4u){ float bf = floorf((vj.z - mnv)/den);
      bf = fminf(fmaxf(bf,0.0f),255.0f); atomicAdd(&hh[(int)bf],1u); cj++; }
    if(bitsJ & 8u){ float bf = floorf((vj.w - mnv)/den);
      bf = fminf(fmaxf(bf,0.0f),255.0f); atomicAdd(&hh[(int)bf],1u); cj++; }
  }
  __syncthreads();                                   // LDS atomics complete
  { unsigned* pcb = pc + (size_t)bid * NBUK;
    for(int i = tid; i < NBUK; i += PT) pcb[i] = buk[i]; }
  if(tid < NB) hisPart[(size_t)bid*NB + tid] = h2[0][tid] + h2[1][tid];

  // qtot: 16 groups of 512 buckets; half-wave shfl reduce (integer-exact)
  { unsigned csum = 0;
    #pragma unroll
    for(int j = 0; j < 16; j++) csum += buk[tid*16 + j] & 0xFFFu;
    csum += __shfl_down(csum, 16, 64);
    csum += __shfl_down(csum,  8, 64);
    csum += __shfl_down(csum,  4, 64);
    csum += __shfl_down(csum,  2, 64);
    csum += __shfl_down(csum,  1, 64);
    if((tid & 31) == 0) qtot[bid*16 + (tid >> 5)] = csum;
  }

  double qd = (double)qacc;
  for(int o = 32; o > 0; o >>= 1){
    qd += __shfl_down(qd, o, 64);
    ci += __shfl_down(ci, o, 64);
    cj += __shfl_down(cj, o, 64);
  }
  if(lane == 0){ dred[wid] = qd; uci[wid] = ci; ucj[wid] = cj; }
  __syncthreads();
  if(tid == 0){
    double t = 0.0; unsigned aci = 0, acj = 0;
    for(int w = 0; w < PT/64; w++){ t += dred[w]; aci += uci[w]; acj += ucj[w]; }
    qp[bid] = t;
    if(c == 0){ cp[2*q] = aci; cp[2*q+1] = acj; }
  }
}

__global__ __launch_bounds__(512) void k_closs(
    const unsigned* __restrict__ pc, const unsigned* __restrict__ qtot,
    const unsigned* __restrict__ hisPart,
    const unsigned* __restrict__ mnp2, const unsigned* __restrict__ mxp2,
    const unsigned* __restrict__ cp, const double* __restrict__ qp,
    double* __restrict__ lossacc, unsigned* __restrict__ donecnt,
    float* __restrict__ out)
{
  const int c = blockIdx.y, qt = blockIdx.x, tid = threadIdx.x;
  const int wid = tid >> 6, lane = tid & 63;
  __shared__ unsigned hsum[NB], qsh[NB];
  __shared__ float cs[NB], hs[NB];
  __shared__ unsigned rmn[4], rmx[4], wsum[8];
  __shared__ double red2[8];
  __shared__ float sh_mn, sh_st;
  __shared__ unsigned sh_base;

  if(tid < K1B){                                     // channel minmax reduce
    unsigned mn = mnp2[c*K1B + tid];
    unsigned mx = mxp2[c*K1B + tid];
    for(int o = 32; o > 0; o >>= 1){
      mn = min(mn, (unsigned)__shfl_down(mn, o, 64));
      mx = max(mx, (unsigned)__shfl_down(mx, o, 64));
    }
    if(lane == 0){ rmn[wid] = mn; rmx[wid] = mx; }
  }
  if(tid < NB){
    unsigned hr = 0u;
    for(int xb = 0; xb < NBLK; xb++) hr += hisPart[(size_t)(c*NBLK + xb)*NB + tid];
    hsum[tid] = hr;
    qsh[tid]  = qtot[c*256 + tid];                   // [sl*16+grp]
  }
  __syncthreads();
  if(tid == 0){
    unsigned mn = min(min(rmn[0],rmn[1]), min(rmn[2],rmn[3]));
    unsigned mx = max(max(rmx[0],rmx[1]), max(rmx[2],rmx[3]));
    float mnv = __uint_as_float(mn);
    sh_mn = mnv;
    sh_st = (__uint_as_float(mx) - mnv) / (float)NB; // remap step (unclamped)
    unsigned ciw = 0, cjw = 0;
    for(int qi = 0; qi < NBLK; qi++){ ciw += cp[2*qi]; cjw += cp[2*qi+1]; }
    float ratio = (float)ciw / (float)cjw;           // nI/nJ in f32, as in ref
    float cum = 0.0f;
    for(int b = 0; b < NB; b++){
      float hh = (float)hsum[b] * ratio;
      hs[b] = hh;
      cum += hh;                                     // sequential f32 == ref rounding
      cs[b] = cum;
    }
    unsigned base = 0;
    for(int sl = 0; sl < NBLK; sl++)
      for(int g2 = 0; g2 < qt; g2++) base += qsh[sl*16 + g2];
    sh_base = base;
  }
  __syncthreads();

  // 1 bucket/thread (b = qt*GBUK + tid); pc via plain coalesced loads
  unsigned  kk = 0;
  long long ss = 0;
  for(int sl = 0; sl < NBLK; sl++){
    unsigned w = pc[(size_t)(c*NBLK + sl)*NBUK + qt*GBUK + tid];
    kk += w & 0xFFFu;  ss += (int)w >> 12;           // sign-extend fx sum
  }
  unsigned v = kk;                                   // wave inclusive scan
  for(int o = 1; o < 64; o <<= 1){
    unsigned t = __shfl_up(v, o, 64);
    if(lane >= o) v += t;
  }
  if(lane == 63) wsum[wid] = v;
  __syncthreads();
  unsigned wbase = 0;
  for(int w = 0; w < wid; w++) wbase += wsum[w];
  unsigned texcl = sh_base + wbase + (v - kk);

  float  mnvf = sh_mn, stepf = sh_st;
  double mnvd = (double)mnvf, stepd = (double)stepf;

  float rf0 = (float)(texcl + 1u);                   // left-search start bin
  int lo = 0, hi = NB;
  while(lo < hi){ int mid = (lo + hi) >> 1; if(cs[mid] < rf0) lo = mid + 1; else hi = mid; }
  int bin = (lo > NB-1) ? NB-1 : lo;

  double acc = 0.0;
  if(kk){
    unsigned ra = texcl + 1u, rb = texcl + kk;
    double sval = 0.0;
    while(ra <= rb){
      while(bin < NB-1 && cs[bin] < (float)ra) bin++;
      float csb = cs[bin], hsb = hs[bin];
      unsigned re = (bin == NB-1) ? rb : min(rb, (unsigned)floorf(csb));
      double lovd = (double)csb - (double)hsb;
      double den2 = fmax((double)hsb, 1e-12);
      double ra_d = (double)ra, re_d = (double)re, nn = (double)(re - ra + 1u);
      double rta = (ra_d - lovd)/den2, rtb = (re_d - lovd)/den2;
      if(hsb > 0.0f && rta >= 0.0 && rtb <= 1.0){
        double sumr = 0.5*(ra_d + re_d)*nn;          // arithmetic series of ranks
        sval += nn*(mnvd + (double)bin*stepd) + stepd*(sumr - nn*lovd)/den2;
      } else {                                       // exact per-rank f32 fallback
        for(unsigned rr = ra; rr <= re; rr++){
          float rf = (float)rr;
          float lov = csb - hsb;
          float rt = (rf - lov) / fmaxf(hsb, 1e-12f);
          rt = fminf(fmaxf(rt, 0.0f), 1.0f);
          sval += (double)(mnvf + ((float)bin + rt)*stepf);
        }
      }
      ra = re + 1u;
    }
    double kb   = (double)kk;
    double cb   = ((double)(qt*GBUK + tid) + 0.5) * (1.0/(double)NBUK);
    double vbar = sval/kb - cb;                      // mean(val) - bucket center
    double S    = (double)ss * FXSI2;                // sum(v - center)
    acc = kb*vbar*vbar - 2.0*vbar*S;
  }
  if(qt == 0 && tid == 0){                           // Q_c once per channel
    double qsum = 0.0;
    for(int qi = 0; qi < NBLK; qi++) qsum += qp[c*NBLK + qi];
    acc += qsum;
  }
  for(int o = 32; o > 0; o >>= 1) acc += __shfl_down(acc, o, 64);
  if(lane == 0) red2[wid] = acc;
  __syncthreads();
  if(tid == 0){
    double t = 0.0;
    for(int w = 0; w < 8; w++) t += red2[w];
    atomicAdd(lossacc, t);
    __threadfence();
    unsigned old = atomicAdd(donecnt, 1u);
    if(old == (unsigned)(CN*NBLK - 1)){              // last block finalizes
      double tot = atomicAdd(lossacc, 0.0);          // coherent read
      out[0] = (float)(tot * (100.0 / (double)((size_t)CN * HWN)));
    }
  }
}

extern "C" void kernel_launch(void* const* d_in, const int* in_sizes, int n_in,
                              void* d_out, int out_size, void* d_ws, size_t ws_size,
                              hipStream_t stream){
  const float* I  = (const float*)d_in[0];
  const float* J  = (const float*)d_in[1];
  const int*   mI = (const int*)d_in[2];
  const int*   mJ = (const int*)d_in[3];
  float* out = (float*)d_out;

  char* base = (char*)d_ws;
  size_t pcB = (size_t)CN * NBLK * NBUK * sizeof(unsigned);      // 32 MB
  unsigned* pc      = (unsigned*)base;
  char* p = base + pcB;
  double*   qp      = (double*)p;   p += (size_t)CN*NBLK*sizeof(double);
  double*   lossacc = (double*)p;   p += sizeof(double);
  unsigned* hisPart = (unsigned*)p; p += (size_t)CN*NBLK*NB*sizeof(unsigned);
  unsigned* qtot    = (unsigned*)p; p += (size_t)CN*NBLK*16*sizeof(unsigned);
  unsigned* mnp2    = (unsigned*)p; p += (size_t)CN*K1B*sizeof(unsigned);
  unsigned* mxp2    = (unsigned*)p; p += (size_t)CN*K1B*sizeof(unsigned);
  unsigned* cp      = (unsigned*)p; p += 2*NBLK*sizeof(unsigned);
  unsigned* donecnt = (unsigned*)p; p += sizeof(unsigned);
  size_t off = (size_t)(p - base); off = (off + 15) & ~(size_t)15;
  unsigned* bIw = (unsigned*)(base + off);                       // 32 KB bits
  unsigned* bJw = bIw + HWN/32;                                  // 32 KB bits

  k_prep<<<K1B, 512, 0, stream>>>(J, mI, mJ, bIw, bJw, mnp2, mxp2,
                                  lossacc, donecnt);
  k_p1h<<<dim3(NBLK, CN), PT, 0, stream>>>(I, J, bIw, bJw, mnp2, mxp2,
                                           pc, qtot, hisPart, cp, qp);
  k_closs<<<dim3(NBLK, CN), 512, 0, stream>>>(pc, qtot, hisPart, mnp2, mxp2,
                                              cp, qp, lossacc, donecnt, out);
}